// Round 8
// baseline (153.227 us; speedup 1.0000x reference)
//
#include <hip/hip_runtime.h>
#include <hip/hip_bf16.h>

typedef unsigned short u16;
typedef __bf16 bf16x8 __attribute__((ext_vector_type(8)));
typedef float f32x4 __attribute__((ext_vector_type(4)));

#define T_TOTAL 8192
#define F_DIM   2048
#define E_NUM   8
#define ER_DIM  128
#define O_DIM   2048

__device__ __forceinline__ u16 f2bf(float f) {
  return __builtin_bit_cast(u16, (__bf16)f);  // RTNE
}
__device__ __forceinline__ unsigned pack2(float a, float b) {
  return (unsigned)f2bf(a) | ((unsigned)f2bf(b) << 16);
}
// async global->LDS, 16B per lane (dest must be wave-uniform-base + lane*16)
__device__ __forceinline__ void gld16(void* lds, const void* g) {
  __builtin_amdgcn_global_load_lds(
      (const __attribute__((address_space(1))) unsigned int*)g,
      (__attribute__((address_space(3))) unsigned int*)lds, 16, 0, 0);
}

// ---------------------------------------------------------------------------
// prep (unchanged, proven): A_stack [E,r,F] f32 -> Abf_sw [128][2048] bf16,
//   XOR-swizzled: Abf_sw[r][c] = A[r][c ^ ((r&7)<<3)]  (bits 3-5, within any
//   64-elem chunk). B_stack [E,O,r] f32 -> BbfT_sw [2048 o][128 er], same.
// ---------------------------------------------------------------------------
__global__ __launch_bounds__(256) void prep_kernel(
    const float* __restrict__ A, const float* __restrict__ Bst,
    u16* __restrict__ Abf, u16* __restrict__ BbfT) {
  const int i = blockIdx.x * 256 + threadIdx.x;  // 0 .. 128*2048-1
  {
    const int r = i >> 11, c = i & 2047;
    Abf[i] = f2bf(A[r * F_DIM + (c ^ ((r & 7) << 3))]);
  }
  {
    const int o = i >> 7, ep = i & 127;
    const int er = ep ^ ((o & 7) << 3);
    const int e = er >> 4, j = er & 15;
    BbfT[i] = f2bf(Bst[e * (O_DIM * 16) + o * 16 + j]);
  }
}

// ---------------------------------------------------------------------------
// gemm1: 16 tokens/block, 256 threads (4 waves), 512 blocks -> 2 blocks/CU
// co-resident (41 KB LDS). BK=64, 32 K-steps, double-buffered DMA staging;
// barrier-drain stalls of one block overlap with the other block's compute.
// Wave w owns er-slice [w*32, w*32+32).
// ---------------------------------------------------------------------------
__global__ __launch_bounds__(256, 2) void gemm1_kernel(
    const float* __restrict__ x, const float* __restrict__ protos,
    const float* __restrict__ scales, const u16* __restrict__ Abf,
    u16* __restrict__ zc) {
  __shared__ u16  as_[2][128 * 64];    // 32 KB  A tiles (swizzled content)
  __shared__ u16  xs [2][16 * 64];     // 4 KB   x tiles bf16 (swizzled)
  __shared__ float pk[2][8 * 64];      // 4 KB   proto chunks f32 (linear)
  __shared__ float sim_lds[16][8];
  __shared__ float w_lds[16][8];

  const int tid  = threadIdx.x;
  const int t0   = blockIdx.x * 16;
  const int row  = tid >> 4;          // 0..15 token
  const int seg  = tid & 15;          // 0..15 k-segment (4 floats each)
  const int lane = tid & 63;
  const int w    = tid >> 6;          // 0..3 wave -> er slice of 32
  const int g    = lane >> 4;
  const int lm   = lane & 15;

  float sacc[E_NUM];
#pragma unroll
  for (int e = 0; e < E_NUM; ++e) sacc[e] = 0.f;
  const f32x4 z4 = {0.f, 0.f, 0.f, 0.f};
  f32x4 acc1[2];
  acc1[0] = z4; acc1[1] = z4;

  // ---- prologue: stage tile 0 ----
#pragma unroll
  for (int it = 0; it < 4; ++it) {
    const int c = it * 256 + tid;            // 16B chunk id, 0..1023
    const int r = c >> 3, ks = (c & 7) * 8;
    gld16(&as_[0][c * 8], Abf + (size_t)r * F_DIM + ks);
  }
  if (tid < 128)
    gld16(&pk[0][tid * 4], protos + (size_t)(tid >> 4) * F_DIM + (tid & 15) * 4);

  const float* xrow = x + (size_t)(t0 + row) * F_DIM + seg * 4;
  f32x4 xv = *reinterpret_cast<const f32x4*>(xrow);
  {
    uint2 hv;
    hv.x = pack2(xv[0], xv[1]); hv.y = pack2(xv[2], xv[3]);
    *reinterpret_cast<uint2*>(
        &xs[0][row * 64 + ((seg * 4) ^ ((row & 7) << 3))]) = hv;
  }

  int buf = 0;
  for (int kt = 0; kt < F_DIM / 64; ++kt) {
    __syncthreads();   // tile kt fully staged (DMA drained + ds_writes)

    f32x4 xn;
    if (kt < 31) {
      const int kb = (kt + 1) * 64;
      // issue next A tile DMA into buf^1
#pragma unroll
      for (int it = 0; it < 4; ++it) {
        const int c = it * 256 + tid;
        const int r = c >> 3, ks = (c & 7) * 8;
        gld16(&as_[buf ^ 1][c * 8], Abf + (size_t)r * F_DIM + kb + ks);
      }
      if (tid < 128)
        gld16(&pk[buf ^ 1][tid * 4],
              protos + (size_t)(tid >> 4) * F_DIM + kb + (tid & 15) * 4);
      // issue next x load (regs)
      xn = *reinterpret_cast<const f32x4*>(xrow + kb);
    }

    // ---- fp32 sim partials (current tile, register xv + LDS pk) ----
#pragma unroll
    for (int e = 0; e < E_NUM; ++e) {
      f32x4 pv = *reinterpret_cast<const f32x4*>(&pk[buf][e * 64 + seg * 4]);
      sacc[e] += xv[0]*pv[0] + xv[1]*pv[1] + xv[2]*pv[2] + xv[3]*pv[3];
    }

    // ---- MFMA: z-slice for er in [w*32, w*32+32) ----
#pragma unroll
    for (int kk = 0; kk < 2; ++kk) {
      const int cb = (kk * 32 + g * 8) ^ ((lm & 7) << 3);
      bf16x8 av = *reinterpret_cast<const bf16x8*>(&xs[buf][lm * 64 + cb]);
#pragma unroll
      for (int n = 0; n < 2; ++n) {
        bf16x8 bv = *reinterpret_cast<const bf16x8*>(
            &as_[buf][(w * 32 + n * 16 + lm) * 64 + cb]);
        acc1[n] = __builtin_amdgcn_mfma_f32_16x16x32_bf16(av, bv, acc1[n], 0, 0, 0);
      }
    }

    if (kt < 31) {
      uint2 hv;
      hv.x = pack2(xn[0], xn[1]); hv.y = pack2(xn[2], xn[3]);
      *reinterpret_cast<uint2*>(
          &xs[buf ^ 1][row * 64 + ((seg * 4) ^ ((row & 7) << 3))]) = hv;
      xv = xn;
    }
    buf ^= 1;
  }

  // ---- sim reduction over the 16 seg-lanes ----
#pragma unroll
  for (int s = 1; s < 16; s <<= 1)
#pragma unroll
    for (int e = 0; e < E_NUM; ++e) sacc[e] += __shfl_xor(sacc[e], s);
  if (seg < E_NUM) sim_lds[row][seg] = sacc[seg];
  __syncthreads();

  // ---- top-2 + softmax + scale ----
  if (tid < 16) {
    float sv[E_NUM];
#pragma unroll
    for (int e = 0; e < E_NUM; ++e) sv[e] = fabsf(sim_lds[tid][e]);
    int e0 = 0; float b0 = sv[0];
#pragma unroll
    for (int e = 1; e < E_NUM; ++e) if (sv[e] > b0) { b0 = sv[e]; e0 = e; }
    int e1 = -1; float b1 = -3.0e38f;
#pragma unroll
    for (int e = 0; e < E_NUM; ++e) if (e != e0 && sv[e] > b1) { b1 = sv[e]; e1 = e; }
    const float d  = __expf(b1 - b0);
    const float c0 = 1.f / (1.f + d);
    const float c1 = d * c0;
#pragma unroll
    for (int e = 0; e < E_NUM; ++e) w_lds[tid][e] = 0.f;
    w_lds[tid][e0] = c0 * scales[e0];
    w_lds[tid][e1] = c1 * scales[e1];
  }
  __syncthreads();

  // ---- epilogue: zc_sw[t][er ^ ((t&7)<<3)] = w[t][e] * z ----
#pragma unroll
  for (int n = 0; n < 2; ++n) {
    const int s2 = w * 2 + n;                  // expert index (er>>4)
    const int er = s2 * 16 + lm;
#pragma unroll
    for (int i = 0; i < 4; ++i) {
      const int tl = g * 4 + i;
      zc[(size_t)(t0 + tl) * ER_DIM + (er ^ ((tl & 7) << 3))] =
          f2bf(acc1[n][i] * w_lds[tl][s2]);
    }
  }
}

// ---------------------------------------------------------------------------
// gemm2 (unchanged, proven): out[8192][2048] f32 = zc_sw @ BbfT_sw^T.
// 64x128 tile, K=128 one-shot, 48 KB LDS -> 3 blocks/CU, 2048 blocks.
// DMA staging, direct accumulator stores (64B quarter-wave segments).
// ---------------------------------------------------------------------------
__global__ __launch_bounds__(256, 3) void gemm2_kernel(
    const u16* __restrict__ zc, const u16* __restrict__ BbfT,
    float* __restrict__ out) {
  __shared__ u16 zcs[64 * 128];    // [64 t][128 er]   16 KB
  __shared__ u16 bbs[128 * 128];   // [128 o][128 er]  32 KB

  const int tid  = threadIdx.x;
  const int o0   = blockIdx.x * 128;
  const int t0   = blockIdx.y * 64;
  const int lane = tid & 63;
  const int w    = tid >> 6;
  const int wm   = w >> 1;         // token half (32)
  const int wn   = w & 1;          // o half (64)
  const int g    = lane >> 4, lm = lane & 15;

#pragma unroll
  for (int it = 0; it < 4; ++it) {
    const int c = it * 256 + tid;                  // 16B chunk, 0..1023
    gld16(&zcs[c * 8], zc + (size_t)t0 * ER_DIM + c * 8);
  }
#pragma unroll
  for (int it = 0; it < 8; ++it) {
    const int c = it * 256 + tid;                  // 16B chunk, 0..2047
    gld16(&bbs[c * 8], BbfT + (size_t)o0 * ER_DIM + c * 8);
  }
  __syncthreads();

  const f32x4 z4 = {0.f, 0.f, 0.f, 0.f};
  f32x4 acc[2][4];
#pragma unroll
  for (int m = 0; m < 2; ++m)
#pragma unroll
    for (int n = 0; n < 4; ++n) acc[m][n] = z4;

#pragma unroll
  for (int kk = 0; kk < 4; ++kk) {
    bf16x8 av[2], bv[4];
#pragma unroll
    for (int m = 0; m < 2; ++m) {
      const int tr = wm * 32 + m * 16 + lm;
      av[m] = *reinterpret_cast<const bf16x8*>(
          &zcs[tr * 128 + ((kk * 32 + g * 8) ^ ((tr & 7) << 3))]);
    }
#pragma unroll
    for (int n = 0; n < 4; ++n) {
      const int orow = wn * 64 + n * 16 + lm;
      bv[n] = *reinterpret_cast<const bf16x8*>(
          &bbs[orow * 128 + ((kk * 32 + g * 8) ^ ((orow & 7) << 3))]);
    }
#pragma unroll
    for (int m = 0; m < 2; ++m)
#pragma unroll
      for (int n = 0; n < 4; ++n)
        acc[m][n] = __builtin_amdgcn_mfma_f32_16x16x32_bf16(av[m], bv[n],
                                                            acc[m][n], 0, 0, 0);
  }

  // direct stores: per (m,n,i) one f32; 16-lane group = 64B contiguous
#pragma unroll
  for (int m = 0; m < 2; ++m) {
#pragma unroll
    for (int n = 0; n < 4; ++n) {
      const int o = o0 + wn * 64 + n * 16 + lm;
#pragma unroll
      for (int i = 0; i < 4; ++i) {
        const int t = t0 + wm * 32 + m * 16 + g * 4 + i;
        out[(size_t)t * O_DIM + o] = acc[m][n][i];
      }
    }
  }
}

// ---------------------------------------------------------------------------
extern "C" void kernel_launch(void* const* d_in, const int* in_sizes, int n_in,
                              void* d_out, int out_size, void* d_ws, size_t ws_size,
                              hipStream_t stream) {
  const float* x      = (const float*)d_in[0];
  const float* protos = (const float*)d_in[1];
  const float* A      = (const float*)d_in[2];
  const float* Bst    = (const float*)d_in[3];
  const float* scales = (const float*)d_in[4];
  // d_in[5] = top_k (always 2)

  u16* zcw  = (u16*)d_ws;                              // 8192*128 bf16 (swizzled)
  u16* Abf  = zcw + (size_t)T_TOTAL * ER_DIM;          // 128*2048 bf16 (swizzled)
  u16* BbfT = Abf + (size_t)ER_DIM * F_DIM;            // 2048*128 bf16 (swizzled)
  float* out = (float*)d_out;

  prep_kernel<<<(ER_DIM * F_DIM) / 256, 256, 0, stream>>>(A, Bst, Abf, BbfT);
  gemm1_kernel<<<T_TOTAL / 16, 256, 0, stream>>>(x, protos, scales, Abf, zcw);
  gemm2_kernel<<<dim3(O_DIM / 128, T_TOTAL / 64), 256, 0, stream>>>(zcw, BbfT, out);
}